// Round 2
// baseline (857.877 us; speedup 1.0000x reference)
//
#include <hip/hip_runtime.h>

// Sinkhorn-Knopp centering, scores [B=16384, K=4096] fp32, eps=0.05, 3 iters.
// Key identity: each rescale overwrites the previous scaling vector, and the
// final column normalization cancels v entirely:
//   out[b,k] = E[b,k]*u3[k] / sum_k E[b,k]*u3[k],  E = exp(scores/eps)
//   u1 = r/colsum(E); v1 = c/(E u1); u2 = r/(E^T v1); v2 = c/(E u2); u3 = r/(E^T v2)
// => 4 streaming passes, exp recomputed each pass (cheap vs. HBM traffic).

#define KCLS 4096
#define INV_EPS 20.0f
#define NBLK 1024
#define NTHR 256

__device__ __forceinline__ float block_sum(float v, float* red) {
  #pragma unroll
  for (int off = 32; off > 0; off >>= 1) v += __shfl_xor(v, off, 64);
  const int wid = threadIdx.x >> 6;
  if ((threadIdx.x & 63) == 0) red[wid] = v;
  __syncthreads();
  const float s = red[0] + red[1] + red[2] + red[3];
  __syncthreads();
  return s;
}

// Pass 1: colsum[k] = sum_b exp(scores[b,k]/eps)
__global__ __launch_bounds__(NTHR) void k_colsum(const float* __restrict__ sc,
                                                 float* __restrict__ colsum,
                                                 int rows) {
  float acc[16];
  #pragma unroll
  for (int i = 0; i < 16; ++i) acc[i] = 0.f;
  const int rows_per = rows / gridDim.x;
  const size_t r0 = (size_t)blockIdx.x * rows_per;
  for (int rr = 0; rr < rows_per; ++rr) {
    const float4* row = (const float4*)(sc + (r0 + rr) * KCLS);
    #pragma unroll
    for (int j = 0; j < 4; ++j) {
      const float4 v = row[threadIdx.x + j * NTHR];
      acc[4 * j + 0] += __expf(v.x * INV_EPS);
      acc[4 * j + 1] += __expf(v.y * INV_EPS);
      acc[4 * j + 2] += __expf(v.z * INV_EPS);
      acc[4 * j + 3] += __expf(v.w * INV_EPS);
    }
  }
  #pragma unroll
  for (int j = 0; j < 4; ++j) {
    const int c = (threadIdx.x + j * NTHR) * 4;
    atomicAdd(&colsum[c + 0], acc[4 * j + 0]);
    atomicAdd(&colsum[c + 1], acc[4 * j + 1]);
    atomicAdd(&colsum[c + 2], acc[4 * j + 2]);
    atomicAdd(&colsum[c + 3], acc[4 * j + 3]);
  }
}

// Passes 2,3: u[k] = coef_u/s_in[k]; per row t = sum_k E*u, v = coef_v/t;
// s_out[k] += sum_rows E[b,k]*v[b]
__global__ __launch_bounds__(NTHR) void k_iter(const float* __restrict__ sc,
                                               const float* __restrict__ s_in,
                                               float* __restrict__ s_out,
                                               int rows, float coef_u, float coef_v) {
  __shared__ float red[4];
  float u[16], acc[16];
  #pragma unroll
  for (int j = 0; j < 4; ++j) {
    const float4 s4 = ((const float4*)s_in)[threadIdx.x + j * NTHR];
    u[4 * j + 0] = coef_u / s4.x;
    u[4 * j + 1] = coef_u / s4.y;
    u[4 * j + 2] = coef_u / s4.z;
    u[4 * j + 3] = coef_u / s4.w;
  }
  #pragma unroll
  for (int i = 0; i < 16; ++i) acc[i] = 0.f;
  const int rows_per = rows / gridDim.x;
  const size_t r0 = (size_t)blockIdx.x * rows_per;
  for (int rr = 0; rr < rows_per; ++rr) {
    const float4* row = (const float4*)(sc + (r0 + rr) * KCLS);
    float e[16];
    float t = 0.f;
    #pragma unroll
    for (int j = 0; j < 4; ++j) {
      const float4 v = row[threadIdx.x + j * NTHR];
      e[4 * j + 0] = __expf(v.x * INV_EPS);
      e[4 * j + 1] = __expf(v.y * INV_EPS);
      e[4 * j + 2] = __expf(v.z * INV_EPS);
      e[4 * j + 3] = __expf(v.w * INV_EPS);
      t += e[4 * j + 0] * u[4 * j + 0] + e[4 * j + 1] * u[4 * j + 1] +
           e[4 * j + 2] * u[4 * j + 2] + e[4 * j + 3] * u[4 * j + 3];
    }
    const float tsum = block_sum(t, red);
    const float vb = coef_v / tsum;
    #pragma unroll
    for (int i = 0; i < 16; ++i) acc[i] += e[i] * vb;
  }
  #pragma unroll
  for (int j = 0; j < 4; ++j) {
    const int c = (threadIdx.x + j * NTHR) * 4;
    atomicAdd(&s_out[c + 0], acc[4 * j + 0]);
    atomicAdd(&s_out[c + 1], acc[4 * j + 1]);
    atomicAdd(&s_out[c + 2], acc[4 * j + 2]);
    atomicAdd(&s_out[c + 3], acc[4 * j + 3]);
  }
}

// Pass 4: u3[k] = coef_u/s_in[k]; out[b,k] = E*u3 / sum_k(E*u3)
__global__ __launch_bounds__(NTHR) void k_final(const float* __restrict__ sc,
                                                const float* __restrict__ s_in,
                                                float* __restrict__ out,
                                                int rows, float coef_u) {
  __shared__ float red[4];
  float u[16];
  #pragma unroll
  for (int j = 0; j < 4; ++j) {
    const float4 s4 = ((const float4*)s_in)[threadIdx.x + j * NTHR];
    u[4 * j + 0] = coef_u / s4.x;
    u[4 * j + 1] = coef_u / s4.y;
    u[4 * j + 2] = coef_u / s4.z;
    u[4 * j + 3] = coef_u / s4.w;
  }
  const int rows_per = rows / gridDim.x;
  const size_t r0 = (size_t)blockIdx.x * rows_per;
  for (int rr = 0; rr < rows_per; ++rr) {
    const float4* row = (const float4*)(sc + (r0 + rr) * KCLS);
    float4* orow = (float4*)(out + (r0 + rr) * KCLS);
    float p[16];
    float t = 0.f;
    #pragma unroll
    for (int j = 0; j < 4; ++j) {
      const float4 v = row[threadIdx.x + j * NTHR];
      p[4 * j + 0] = __expf(v.x * INV_EPS) * u[4 * j + 0];
      p[4 * j + 1] = __expf(v.y * INV_EPS) * u[4 * j + 1];
      p[4 * j + 2] = __expf(v.z * INV_EPS) * u[4 * j + 2];
      p[4 * j + 3] = __expf(v.w * INV_EPS) * u[4 * j + 3];
      t += p[4 * j + 0] + p[4 * j + 1] + p[4 * j + 2] + p[4 * j + 3];
    }
    const float denom = block_sum(t, red);
    const float inv = 1.0f / denom;
    #pragma unroll
    for (int j = 0; j < 4; ++j) {
      float4 o;
      o.x = p[4 * j + 0] * inv;
      o.y = p[4 * j + 1] * inv;
      o.z = p[4 * j + 2] * inv;
      o.w = p[4 * j + 3] * inv;
      orow[threadIdx.x + j * NTHR] = o;
    }
  }
}

extern "C" void kernel_launch(void* const* d_in, const int* in_sizes, int n_in,
                              void* d_out, int out_size, void* d_ws, size_t ws_size,
                              hipStream_t stream) {
  const float* sc = (const float*)d_in[0];
  float* out = (float*)d_out;
  const int B = in_sizes[0] / KCLS;

  float* colsum = (float*)d_ws;     // KCLS floats
  float* s2 = colsum + KCLS;        // KCLS floats
  float* s3 = s2 + KCLS;            // KCLS floats
  hipMemsetAsync(d_ws, 0, 3 * KCLS * sizeof(float), stream);

  const float r = 1.0f / (float)KCLS;
  const float c = 1.0f / (float)B;

  dim3 grid(NBLK), blk(NTHR);
  k_colsum<<<grid, blk, 0, stream>>>(sc, colsum, B);
  k_iter<<<grid, blk, 0, stream>>>(sc, colsum, s2, B, r, c);
  k_iter<<<grid, blk, 0, stream>>>(sc, s2, s3, B, r, c);
  k_final<<<grid, blk, 0, stream>>>(sc, s3, out, B, r);
}